// Round 10
// baseline (633.851 us; speedup 1.0000x reference)
//
#include <hip/hip_runtime.h>
#include <math.h>

#define B_    4
#define CIN_  32
#define COUT_ 64
#define H_    192
#define W_    192
#define HW_   (H_ * W_)        // 36864
#define NPIX_ (B_ * HW_)       // 147456
#define EPS_  1e-5f

// XCD-aware swizzle: grid 1152 = 8 XCDs * 144. Proven R7: FETCH 300->15.5 MB.
static __device__ __forceinline__ int swz1152(int blk) {
    return ((blk & 7) * 144) + (blk >> 3);
}

struct Cr { int o00, o01, o10, o11; float w00, w01, w10, w11; };

// ---------------------------------------------------------------------------
// Kernel 0: fused prep. Blocks [0,576): transpose x (NCHW) -> xt (NHWC).
// Blocks [576,673): weight transposes + stats zeroing.
// ---------------------------------------------------------------------------
__global__ __launch_bounds__(256) void k_pre(
    const float* __restrict__ x, const float* __restrict__ w_def,
    const float* __restrict__ w_off, float* __restrict__ xt,
    float* __restrict__ wt_def, float* __restrict__ wt_off,
    float* __restrict__ stats)
{
    if (blockIdx.x < NPIX_ / 256) {
        const int pid = blockIdx.x * 256 + threadIdx.x;
        const int b   = pid / HW_;
        const int rem = pid - b * HW_;
        const float* xb = x + (size_t)b * CIN_ * HW_ + rem;
        float4 v[8];
#pragma unroll
        for (int j = 0; j < 8; ++j) {
            v[j].x = xb[(j * 4 + 0) * HW_];
            v[j].y = xb[(j * 4 + 1) * HW_];
            v[j].z = xb[(j * 4 + 2) * HW_];
            v[j].w = xb[(j * 4 + 3) * HW_];
        }
        float4* dst = (float4*)(xt + (size_t)pid * 32);
#pragma unroll
        for (int j = 0; j < 8; ++j) dst[j] = v[j];
    } else {
        const int i = (blockIdx.x - NPIX_ / 256) * 256 + threadIdx.x;
        if (i < 18432) {                       // wt_def[kk][c][o64]
            const int o  = i & 63;
            const int c  = (i >> 6) & 31;
            const int kk = i >> 11;
            wt_def[i] = w_def[(o * 32 + c) * 9 + kk];
        } else if (i < 18432 + 5760) {         // wt_off[kk][c][o20]
            const int e  = i - 18432;
            const int o  = e % 20;
            const int t  = e / 20;
            const int c  = t & 31;
            const int kk = t >> 5;
            wt_off[e] = (o < 18) ? w_off[(o * 32 + c) * 9 + kk] : 0.f;
        } else if (i < 18432 + 5760 + 512) {
            stats[i - 18432 - 5760] = 0.f;     // sum_bc + sumsq_bc
        }
    }
}

// ---------------------------------------------------------------------------
// Kernel 1: offsets conv (32 -> 18 ch). 512 threads per 128 px.
// Phase-1 lane map: px1 = tid>>2, g1 = tid&3 -> 4 consecutive lanes cover
// one pixel's 128 B tap contiguously (<=32 lines/instr vs 64).
// Partial acc[20] over channels [8g1,+8); LDS reduce (layout (px*4+g)*21,
// ~2-way max); reduce phase uses px2 = tid&127, jg = tid>>7.
// ---------------------------------------------------------------------------
__global__ __launch_bounds__(512, 6) void k_conv_off(
    const float* __restrict__ xt, const float* __restrict__ wt,
    const float* __restrict__ b_off, float* __restrict__ offs)
{
    __shared__ float rlds[512 * 21];
    const int tid = threadIdx.x;
    const int px1 = tid >> 2;
    const int g1  = tid & 3;
    const int px2 = tid & 127;
    const int jg  = __builtin_amdgcn_readfirstlane(tid >> 7);

    const int base = swz1152(blockIdx.x) * 128;
    const int b    = base / HW_;
    const int rb   = base - b * HW_;
    const int rem1 = rb + px1;
    const int h    = rem1 / W_;
    const int w    = rem1 - h * W_;
    const float* xg = xt + (size_t)b * HW_ * 32 + g1 * 8;

    float acc[20];
#pragma unroll
    for (int o = 0; o < 20; ++o) acc[o] = 0.f;

    auto tapoff = [&](int kk, float& g) -> int {
        const int yy = h + kk / 3 - 1;
        const int sx = w + kk % 3 - 1;
        const bool ok = (yy >= 0) & (yy < H_) & (sx >= 0) & (sx < W_);
        g = ok ? 1.f : 0.f;
        const int cy = min(max(yy, 0), H_ - 1);
        const int cx = min(max(sx, 0), W_ - 1);
        return (cy * W_ + cx) * 32;
    };

    float g; int off = tapoff(0, g);
    float4 x0 = *(const float4*)(xg + off);
    float4 x1 = *(const float4*)(xg + off + 4);

#pragma unroll 1
    for (int kk = 0; kk < 9; ++kk) {
        float ng = 0.f; float4 nx0, nx1;
        if (kk < 8) {                           // prefetch next tap
            const int noff = tapoff(kk + 1, ng);
            nx0 = *(const float4*)(xg + noff);
            nx1 = *(const float4*)(xg + noff + 4);
        }
        const float vs[8] = {x0.x * g, x0.y * g, x0.z * g, x0.w * g,
                             x1.x * g, x1.y * g, x1.z * g, x1.w * g};
#pragma unroll
        for (int e = 0; e < 8; ++e) {
            const float4* wr = (const float4*)(wt + (kk * 32 + g1 * 8 + e) * 20);
            const float a = vs[e];
#pragma unroll
            for (int q = 0; q < 5; ++q) {
                float4 wv = wr[q];
                acc[q * 4 + 0] += a * wv.x;
                acc[q * 4 + 1] += a * wv.y;
                acc[q * 4 + 2] += a * wv.z;
                acc[q * 4 + 3] += a * wv.w;
            }
        }
        x0 = nx0; x1 = nx1; g = ng;
    }

    float* rp = &rlds[(px1 * 4 + g1) * 21];
#pragma unroll
    for (int o = 0; o < 20; ++o) rp[o] = acc[o];
    __syncthreads();

    const int rem2 = rb + px2;
#pragma unroll
    for (int j = 0; j < 5; ++j) {
        const int o = jg * 5 + j;
        if (o < 18) {
            const float s = rlds[(px2 * 4 + 0) * 21 + o]
                          + rlds[(px2 * 4 + 1) * 21 + o]
                          + rlds[(px2 * 4 + 2) * 21 + o]
                          + rlds[(px2 * 4 + 3) * 21 + o];
            offs[(b * 18 + o) * HW_ + rem2] = s + b_off[o];
        }
    }
}

// ---------------------------------------------------------------------------
// Kernel 2: deformable conv + fused BN stats. 512 threads per 128 px.
// Phase 1 (per kk): lane map px1 = tid>>2, g1 = tid&3 -> 4 consecutive
// lanes gather one pixel's 4 corners contiguously (<=32 lines/instr).
// Bilinear v[8] -> LDS [px][c] (pad 36) via 2x ds_write_b128. Next kk's
// corners issued before phase 2 (fly across the barrier).
// Phase 2: px2 = tid&127, og = tid>>7 (uniform -> s_load weights);
// 8x ds_read_b128 + 512 FMA per kk into acc[16].
// Epilogue: bias+store+wave butterfly stats.
// ---------------------------------------------------------------------------
__global__ __launch_bounds__(512, 6) void k_deform(
    const float* __restrict__ xt, const float* __restrict__ offs,
    const float* __restrict__ wt, const float* __restrict__ b_def,
    float* __restrict__ y, float* __restrict__ sum_bc,
    float* __restrict__ sumsq_bc)
{
    __shared__ float vlds[128 * 36];           // [px][c] pad 36, 18.4 KB
    const int tid  = threadIdx.x;
    const int px1  = tid >> 2;
    const int g1   = tid & 3;
    const int px2  = tid & 127;
    const int og   = __builtin_amdgcn_readfirstlane(tid >> 7);
    const int lane = tid & 63;

    const int base = swz1152(blockIdx.x) * 128;
    const int b    = base / HW_;
    const int rb   = base - b * HW_;
    const int rem1 = rb + px1;
    const int h    = rem1 / W_;
    const int w    = rem1 - h * W_;
    const float* xg = xt + (size_t)b * HW_ * 32 + g1 * 8;
    const float* ob = offs + b * 18 * HW_ + rem1;

    float acc[16];
#pragma unroll
    for (int q = 0; q < 16; ++q) acc[q] = 0.f;

    auto mk = [&](int kk, float dy, float dx) -> Cr {
        const float py = (float)(h + kk / 3 - 1) + dy;
        const float qx = (float)(w + kk % 3 - 1) + dx;
        const float y0f = floorf(py), x0f = floorf(qx);
        const float wy = py - y0f, wx = qx - x0f;
        const int iy0 = (int)y0f, ix0 = (int)x0f;
        const int iy1 = iy0 + 1,  ix1 = ix0 + 1;
        const float vy0 = (iy0 >= 0 && iy0 < H_) ? 1.f : 0.f;
        const float vy1 = (iy1 >= 0 && iy1 < H_) ? 1.f : 0.f;
        const float vx0 = (ix0 >= 0 && ix0 < W_) ? 1.f : 0.f;
        const float vx1 = (ix1 >= 0 && ix1 < W_) ? 1.f : 0.f;
        Cr c;
        c.w00 = (1.f - wy) * (1.f - wx) * vy0 * vx0;
        c.w01 = (1.f - wy) * wx * vy0 * vx1;
        c.w10 = wy * (1.f - wx) * vy1 * vx0;
        c.w11 = wy * wx * vy1 * vx1;
        const int cy0 = min(max(iy0, 0), H_ - 1), cy1 = min(max(iy1, 0), H_ - 1);
        const int cx0 = min(max(ix0, 0), W_ - 1), cx1 = min(max(ix1, 0), W_ - 1);
        c.o00 = (cy0 * W_ + cx0) * 32; c.o01 = (cy0 * W_ + cx1) * 32;
        c.o10 = (cy1 * W_ + cx0) * 32; c.o11 = (cy1 * W_ + cx1) * 32;
        return c;
    };

    float dy = ob[0], dx = ob[HW_];
    Cr cur = mk(0, dy, dx);
    float4 A0 = *(const float4*)(xg + cur.o00), A1 = *(const float4*)(xg + cur.o00 + 4);
    float4 B0 = *(const float4*)(xg + cur.o01), B1 = *(const float4*)(xg + cur.o01 + 4);
    float4 C0 = *(const float4*)(xg + cur.o10), C1 = *(const float4*)(xg + cur.o10 + 4);
    float4 D0 = *(const float4*)(xg + cur.o11), D1 = *(const float4*)(xg + cur.o11 + 4);
    float ndy = ob[2 * HW_], ndx = ob[3 * HW_];

#pragma unroll 1
    for (int kk = 0; kk < 9; ++kk) {
        __syncthreads();                       // previous phase-2 reads done
        float4 v0, v1;
        v0.x = cur.w00 * A0.x + cur.w01 * B0.x + cur.w10 * C0.x + cur.w11 * D0.x;
        v0.y = cur.w00 * A0.y + cur.w01 * B0.y + cur.w10 * C0.y + cur.w11 * D0.y;
        v0.z = cur.w00 * A0.z + cur.w01 * B0.z + cur.w10 * C0.z + cur.w11 * D0.z;
        v0.w = cur.w00 * A0.w + cur.w01 * B0.w + cur.w10 * C0.w + cur.w11 * D0.w;
        v1.x = cur.w00 * A1.x + cur.w01 * B1.x + cur.w10 * C1.x + cur.w11 * D1.x;
        v1.y = cur.w00 * A1.y + cur.w01 * B1.y + cur.w10 * C1.y + cur.w11 * D1.y;
        v1.z = cur.w00 * A1.z + cur.w01 * B1.z + cur.w10 * C1.z + cur.w11 * D1.z;
        v1.w = cur.w00 * A1.w + cur.w01 * B1.w + cur.w10 * C1.w + cur.w11 * D1.w;
        *(float4*)&vlds[px1 * 36 + g1 * 8]     = v0;
        *(float4*)&vlds[px1 * 36 + g1 * 8 + 4] = v1;

        if (kk < 8) {                          // issue next kk's gathers now
            cur = mk(kk + 1, ndy, ndx);
            A0 = *(const float4*)(xg + cur.o00); A1 = *(const float4*)(xg + cur.o00 + 4);
            B0 = *(const float4*)(xg + cur.o01); B1 = *(const float4*)(xg + cur.o01 + 4);
            C0 = *(const float4*)(xg + cur.o10); C1 = *(const float4*)(xg + cur.o10 + 4);
            D0 = *(const float4*)(xg + cur.o11); D1 = *(const float4*)(xg + cur.o11 + 4);
            if (kk < 7) {
                ndy = ob[(2 * kk + 4) * HW_];
                ndx = ob[(2 * kk + 5) * HW_];
            }
        }
        __syncthreads();                       // v(kk) visible

        const float* wk = wt + (kk << 11) + (og << 4);   // wt[kk][.][16og]
        const float* vp = &vlds[px2 * 36];
#pragma unroll
        for (int j = 0; j < 8; ++j) {
            const float4 vv = *(const float4*)(vp + 4 * j);   // ds_read_b128
            const float vs[4] = {vv.x, vv.y, vv.z, vv.w};
#pragma unroll
            for (int e = 0; e < 4; ++e) {
                const float4* wr = (const float4*)(wk + ((j * 4 + e) << 6));
                const float4 w0 = wr[0], w1 = wr[1], w2 = wr[2], w3 = wr[3];
                const float vc = vs[e];
                acc[ 0] += vc * w0.x; acc[ 1] += vc * w0.y;
                acc[ 2] += vc * w0.z; acc[ 3] += vc * w0.w;
                acc[ 4] += vc * w1.x; acc[ 5] += vc * w1.y;
                acc[ 6] += vc * w1.z; acc[ 7] += vc * w1.w;
                acc[ 8] += vc * w2.x; acc[ 9] += vc * w2.y;
                acc[10] += vc * w2.z; acc[11] += vc * w2.w;
                acc[12] += vc * w3.x; acc[13] += vc * w3.y;
                acc[14] += vc * w3.z; acc[15] += vc * w3.w;
            }
        }
    }

    // bias + store (16 channels for this og, pixel rem2)
    const int rem2 = rb + px2;
    float* yp = y + ((size_t)b * COUT_ + og * 16) * HW_ + rem2;
#pragma unroll
    for (int q = 0; q < 16; ++q) {
        acc[q] += b_def[og * 16 + q];
        yp[q * HW_] = acc[q];
    }

    // fused BN stats: wave = (64 px, one og). Butterfly 16 channels.
    float ls = 0.f, lq = 0.f;
#pragma unroll
    for (int o = 0; o < 16; ++o) {
        float t = acc[o];
        float u = t * t;
#pragma unroll
        for (int s = 32; s; s >>= 1) {
            t += __shfl_xor(t, s, 64);
            u += __shfl_xor(u, s, 64);
        }
        if (lane == o) { ls = t; lq = u; }
    }
    if (lane < 16) {
        atomicAdd(&sum_bc[b * 64 + og * 16 + lane], ls);
        atomicAdd(&sumsq_bc[b * 64 + og * 16 + lane], lq);
    }
}

// ---------------------------------------------------------------------------
// Kernel 3: fused SE-MLP + affine(BN*SE) + ReLU + 2x2 maxpool.
// ---------------------------------------------------------------------------
__global__ __launch_bounds__(256) void k_finish(
    const float* __restrict__ y,
    const float* __restrict__ sum_bc, const float* __restrict__ sumsq_bc,
    const float* __restrict__ gamma, const float* __restrict__ beta,
    const float* __restrict__ fc1_w, const float* __restrict__ fc1_b,
    const float* __restrict__ fc2_w, const float* __restrict__ fc2_b,
    float* __restrict__ out)
{
    __shared__ float sal[256], sbb[256], sin_[256];
    const int tid = threadIdx.x;
    {
        const int b = tid >> 6, c = tid & 63;
        float ch_s = 0.f, ch_q = 0.f;
#pragma unroll
        for (int bb = 0; bb < 4; ++bb) {
            ch_s += sum_bc[bb * 64 + c];
            ch_q += sumsq_bc[bb * 64 + c];
        }
        const float invN = 1.f / (float)(B_ * HW_);
        const float mean = ch_s * invN;
        const float var  = ch_q * invN - mean * mean;
        const float a    = gamma[c] * rsqrtf(var + EPS_);
        const float bi   = beta[c] - mean * a;
        sin_[tid] = a * (sum_bc[tid] * (1.f / (float)HW_)) + bi;
        __syncthreads();
        float hv[4];
#pragma unroll
        for (int j = 0; j < 4; ++j) {
            float hs = fc1_b[j];
            for (int cc = 0; cc < 64; ++cc)
                hs += sin_[b * 64 + cc] * fc1_w[j * 64 + cc];
            hv[j] = fmaxf(hs, 0.f);
        }
        float o = fc2_b[c];
#pragma unroll
        for (int j = 0; j < 4; ++j) o += hv[j] * fc2_w[c * 4 + j];
        const float s = 1.f / (1.f + expf(-o));
        sal[tid] = a * s;
        sbb[tid] = bi * s;
    }
    __syncthreads();

    const int t    = blockIdx.x * 256 + tid;
    const int opix = t * 2;
    const int bc   = opix / (96 * 96);
    const int rem  = opix - bc * (96 * 96);
    const int oh   = rem / 96, ow = rem - oh * 96;   // ow even
    const float al = sal[bc], bb = sbb[bc];
    const float* yp = y + (size_t)bc * HW_ + (2 * oh) * W_ + 2 * ow;
    const float4 r0 = *(const float4*)yp;
    const float4 r1 = *(const float4*)(yp + W_);
    float2 st;
    st.x = fmaxf(fmaxf(fmaxf(fmaf(r0.x, al, bb), fmaf(r0.y, al, bb)),
                       fmaxf(fmaf(r1.x, al, bb), fmaf(r1.y, al, bb))), 0.f);
    st.y = fmaxf(fmaxf(fmaxf(fmaf(r0.z, al, bb), fmaf(r0.w, al, bb)),
                       fmaxf(fmaf(r1.z, al, bb), fmaf(r1.w, al, bb))), 0.f);
    *(float2*)(out + opix) = st;
}

// ---------------------------------------------------------------------------
extern "C" void kernel_launch(void* const* d_in, const int* in_sizes, int n_in,
                              void* d_out, int out_size, void* d_ws, size_t ws_size,
                              hipStream_t stream)
{
    const float* x     = (const float*)d_in[0];
    const float* w_off = (const float*)d_in[1];
    const float* b_off = (const float*)d_in[2];
    const float* w_def = (const float*)d_in[3];
    const float* b_def = (const float*)d_in[4];
    const float* gamma = (const float*)d_in[5];
    const float* beta  = (const float*)d_in[6];
    const float* fc1_w = (const float*)d_in[7];
    const float* fc1_b = (const float*)d_in[8];
    const float* fc2_w = (const float*)d_in[9];
    const float* fc2_b = (const float*)d_in[10];
    float* out = (float*)d_out;

    float* ws   = (float*)d_ws;
    float* offs   = ws;                          // 2,654,208 floats
    float* yb     = offs + 2654208;              // 9,437,184 floats
    float* xt     = yb + 9437184;                // 4,718,592 floats (NHWC x)
    float* wt_def = xt + 4718592;                // 18,432
    float* wt_off = wt_def + 18432;              // 5,760
    float* stats  = wt_off + 5760;               // 1,024
    float* sum_bc   = stats;
    float* sumsq_bc = stats + 256;

    k_pre     <<<dim3(NPIX_ / 256 + 97), dim3(256), 0, stream>>>(
                  x, w_def, w_off, xt, wt_def, wt_off, stats);
    k_conv_off<<<dim3(NPIX_ / 128), dim3(512), 0, stream>>>(xt, wt_off, b_off, offs);
    k_deform  <<<dim3(NPIX_ / 128), dim3(512), 0, stream>>>(xt, offs, wt_def, b_def,
                                                            yb, sum_bc, sumsq_bc);
    k_finish  <<<dim3(B_ * COUT_ * 96 * 96 / 512), dim3(256), 0, stream>>>(
                  yb, sum_bc, sumsq_bc, gamma, beta,
                  fc1_w, fc1_b, fc2_w, fc2_b, out);
}

// Round 11
// 283.842 us; speedup vs baseline: 2.2331x; 2.2331x over previous
//
#include <hip/hip_runtime.h>
#include <math.h>

#define B_    4
#define CIN_  32
#define COUT_ 64
#define H_    192
#define W_    192
#define HW_   (H_ * W_)        // 36864
#define NPIX_ (B_ * HW_)       // 147456
#define EPS_  1e-5f

// XCD-aware swizzle: grid 1152 = 8 XCDs * 144. Proven R7: FETCH 300->15.5 MB.
static __device__ __forceinline__ int swz1152(int blk) {
    return ((blk & 7) * 144) + (blk >> 3);
}

struct Cr { int o00, o01, o10, o11; float w00, w01, w10, w11; };

// ---------------------------------------------------------------------------
// Kernel 0: fused prep. Blocks [0,576): transpose x (NCHW) -> xt (NHWC).
// Blocks [576,673): weight transposes + stats zeroing.
// wt_def[kk][c][o64]; wt_off now [kk][o20][c32] (rows of 32 ch per output,
// o>=18 zero) so conv_off phase-2 reads are uniform s_load dot-products.
// ---------------------------------------------------------------------------
__global__ __launch_bounds__(256) void k_pre(
    const float* __restrict__ x, const float* __restrict__ w_def,
    const float* __restrict__ w_off, float* __restrict__ xt,
    float* __restrict__ wt_def, float* __restrict__ wt_off,
    float* __restrict__ stats)
{
    if (blockIdx.x < NPIX_ / 256) {
        const int pid = blockIdx.x * 256 + threadIdx.x;
        const int b   = pid / HW_;
        const int rem = pid - b * HW_;
        const float* xb = x + (size_t)b * CIN_ * HW_ + rem;
        float4 v[8];
#pragma unroll
        for (int j = 0; j < 8; ++j) {
            v[j].x = xb[(j * 4 + 0) * HW_];
            v[j].y = xb[(j * 4 + 1) * HW_];
            v[j].z = xb[(j * 4 + 2) * HW_];
            v[j].w = xb[(j * 4 + 3) * HW_];
        }
        float4* dst = (float4*)(xt + (size_t)pid * 32);
#pragma unroll
        for (int j = 0; j < 8; ++j) dst[j] = v[j];
    } else {
        const int i = (blockIdx.x - NPIX_ / 256) * 256 + threadIdx.x;
        if (i < 18432) {                       // wt_def[kk][c][o64]
            const int o  = i & 63;
            const int c  = (i >> 6) & 31;
            const int kk = i >> 11;
            wt_def[i] = w_def[(o * 32 + c) * 9 + kk];
        } else if (i < 18432 + 5760) {         // wt_off[kk][o20][c32]
            const int e  = i - 18432;
            const int c  = e & 31;
            const int t  = e >> 5;
            const int o  = t % 20;
            const int kk = t / 20;
            wt_off[e] = (o < 18) ? w_off[(o * 32 + c) * 9 + kk] : 0.f;
        } else if (i < 18432 + 5760 + 512) {
            stats[i - 18432 - 5760] = 0.f;     // sum_bc + sumsq_bc
        }
    }
}

// ---------------------------------------------------------------------------
// Kernel 1: offsets conv (32 -> 18 ch), deform-mirror two-phase form.
// Phase 1 (per kk): thread (px1=tid>>2, g1=tid&3) loads its pixel's tap
// channels [8g1,+8) (4 consecutive lanes cover the 128 B contiguously),
// gates, writes LDS [px][36] (2x ds_write_b128, contiguous-equivalent).
// Next tap prefetched before phase 2.
// Phase 2: px2=tid&127, og=tid>>7 (UNIFORM -> s_load weights): 5 outputs
// [5og,+5) as dot-products over the 32 LDS channels (8x ds_read_b128).
// ---------------------------------------------------------------------------
__global__ __launch_bounds__(512, 6) void k_conv_off(
    const float* __restrict__ xt, const float* __restrict__ wt,
    const float* __restrict__ b_off, float* __restrict__ offs)
{
    __shared__ float vlds[128 * 36];
    const int tid = threadIdx.x;
    const int px1 = tid >> 2;
    const int g1  = tid & 3;
    const int px2 = tid & 127;
    const int og  = __builtin_amdgcn_readfirstlane(tid >> 7);

    const int base = swz1152(blockIdx.x) * 128;
    const int b    = base / HW_;
    const int rb   = base - b * HW_;
    const int rem1 = rb + px1;
    const int h    = rem1 / W_;
    const int w    = rem1 - h * W_;
    const float* xg = xt + (size_t)b * HW_ * 32 + g1 * 8;

    float acc[5];
#pragma unroll
    for (int o = 0; o < 5; ++o) acc[o] = 0.f;

    auto tapoff = [&](int kk, float& g) -> int {
        const int yy = h + kk / 3 - 1;
        const int sx = w + kk % 3 - 1;
        const bool ok = (yy >= 0) & (yy < H_) & (sx >= 0) & (sx < W_);
        g = ok ? 1.f : 0.f;
        const int cy = min(max(yy, 0), H_ - 1);
        const int cx = min(max(sx, 0), W_ - 1);
        return (cy * W_ + cx) * 32;
    };

    float g; int off = tapoff(0, g);
    float4 x0 = *(const float4*)(xg + off);
    float4 x1 = *(const float4*)(xg + off + 4);

#pragma unroll 1
    for (int kk = 0; kk < 9; ++kk) {
        __syncthreads();                      // prev phase-2 reads done
        float4 s0, s1;
        s0.x = x0.x * g; s0.y = x0.y * g; s0.z = x0.z * g; s0.w = x0.w * g;
        s1.x = x1.x * g; s1.y = x1.y * g; s1.z = x1.z * g; s1.w = x1.w * g;
        *(float4*)&vlds[px1 * 36 + g1 * 8]     = s0;
        *(float4*)&vlds[px1 * 36 + g1 * 8 + 4] = s1;

        if (kk < 8) {                         // prefetch next tap (flies
            const int noff = tapoff(kk + 1, g);   // across the barrier)
            x0 = *(const float4*)(xg + noff);
            x1 = *(const float4*)(xg + noff + 4);
        }
        __syncthreads();                      // tap(kk) visible

        const float* vp = &vlds[px2 * 36];
        float4 vv[8];
#pragma unroll
        for (int j = 0; j < 8; ++j) vv[j] = *(const float4*)(vp + 4 * j);

        const float* wk = wt + (kk * 20 + og * 5) * 32;   // [kk][5og..][c32]
#pragma unroll
        for (int oo = 0; oo < 5; ++oo) {
            const float4* wr = (const float4*)(wk + oo * 32);
            float s = acc[oo];
#pragma unroll
            for (int j = 0; j < 8; ++j) {
                const float4 wv = wr[j];
                s += vv[j].x * wv.x + vv[j].y * wv.y
                   + vv[j].z * wv.z + vv[j].w * wv.w;
            }
            acc[oo] = s;
        }
    }

    const int rem2 = rb + px2;
#pragma unroll
    for (int oo = 0; oo < 5; ++oo) {
        const int o = og * 5 + oo;
        if (o < 18)
            offs[(b * 18 + o) * HW_ + rem2] = acc[oo] + b_off[o];
    }
}

// ---------------------------------------------------------------------------
// Kernel 2: deformable conv + fused BN stats. (Unchanged from R10.)
// ---------------------------------------------------------------------------
__global__ __launch_bounds__(512, 6) void k_deform(
    const float* __restrict__ xt, const float* __restrict__ offs,
    const float* __restrict__ wt, const float* __restrict__ b_def,
    float* __restrict__ y, float* __restrict__ sum_bc,
    float* __restrict__ sumsq_bc)
{
    __shared__ float vlds[128 * 36];           // [px][c] pad 36, 18.4 KB
    const int tid  = threadIdx.x;
    const int px1  = tid >> 2;
    const int g1   = tid & 3;
    const int px2  = tid & 127;
    const int og   = __builtin_amdgcn_readfirstlane(tid >> 7);
    const int lane = tid & 63;

    const int base = swz1152(blockIdx.x) * 128;
    const int b    = base / HW_;
    const int rb   = base - b * HW_;
    const int rem1 = rb + px1;
    const int h    = rem1 / W_;
    const int w    = rem1 - h * W_;
    const float* xg = xt + (size_t)b * HW_ * 32 + g1 * 8;
    const float* ob = offs + b * 18 * HW_ + rem1;

    float acc[16];
#pragma unroll
    for (int q = 0; q < 16; ++q) acc[q] = 0.f;

    auto mk = [&](int kk, float dy, float dx) -> Cr {
        const float py = (float)(h + kk / 3 - 1) + dy;
        const float qx = (float)(w + kk % 3 - 1) + dx;
        const float y0f = floorf(py), x0f = floorf(qx);
        const float wy = py - y0f, wx = qx - x0f;
        const int iy0 = (int)y0f, ix0 = (int)x0f;
        const int iy1 = iy0 + 1,  ix1 = ix0 + 1;
        const float vy0 = (iy0 >= 0 && iy0 < H_) ? 1.f : 0.f;
        const float vy1 = (iy1 >= 0 && iy1 < H_) ? 1.f : 0.f;
        const float vx0 = (ix0 >= 0 && ix0 < W_) ? 1.f : 0.f;
        const float vx1 = (ix1 >= 0 && ix1 < W_) ? 1.f : 0.f;
        Cr c;
        c.w00 = (1.f - wy) * (1.f - wx) * vy0 * vx0;
        c.w01 = (1.f - wy) * wx * vy0 * vx1;
        c.w10 = wy * (1.f - wx) * vy1 * vx0;
        c.w11 = wy * wx * vy1 * vx1;
        const int cy0 = min(max(iy0, 0), H_ - 1), cy1 = min(max(iy1, 0), H_ - 1);
        const int cx0 = min(max(ix0, 0), W_ - 1), cx1 = min(max(ix1, 0), W_ - 1);
        c.o00 = (cy0 * W_ + cx0) * 32; c.o01 = (cy0 * W_ + cx1) * 32;
        c.o10 = (cy1 * W_ + cx0) * 32; c.o11 = (cy1 * W_ + cx1) * 32;
        return c;
    };

    float dy = ob[0], dx = ob[HW_];
    Cr cur = mk(0, dy, dx);
    float4 A0 = *(const float4*)(xg + cur.o00), A1 = *(const float4*)(xg + cur.o00 + 4);
    float4 B0 = *(const float4*)(xg + cur.o01), B1 = *(const float4*)(xg + cur.o01 + 4);
    float4 C0 = *(const float4*)(xg + cur.o10), C1 = *(const float4*)(xg + cur.o10 + 4);
    float4 D0 = *(const float4*)(xg + cur.o11), D1 = *(const float4*)(xg + cur.o11 + 4);
    float ndy = ob[2 * HW_], ndx = ob[3 * HW_];

#pragma unroll 1
    for (int kk = 0; kk < 9; ++kk) {
        __syncthreads();                       // previous phase-2 reads done
        float4 v0, v1;
        v0.x = cur.w00 * A0.x + cur.w01 * B0.x + cur.w10 * C0.x + cur.w11 * D0.x;
        v0.y = cur.w00 * A0.y + cur.w01 * B0.y + cur.w10 * C0.y + cur.w11 * D0.y;
        v0.z = cur.w00 * A0.z + cur.w01 * B0.z + cur.w10 * C0.z + cur.w11 * D0.z;
        v0.w = cur.w00 * A0.w + cur.w01 * B0.w + cur.w10 * C0.w + cur.w11 * D0.w;
        v1.x = cur.w00 * A1.x + cur.w01 * B1.x + cur.w10 * C1.x + cur.w11 * D1.x;
        v1.y = cur.w00 * A1.y + cur.w01 * B1.y + cur.w10 * C1.y + cur.w11 * D1.y;
        v1.z = cur.w00 * A1.z + cur.w01 * B1.z + cur.w10 * C1.z + cur.w11 * D1.z;
        v1.w = cur.w00 * A1.w + cur.w01 * B1.w + cur.w10 * C1.w + cur.w11 * D1.w;
        *(float4*)&vlds[px1 * 36 + g1 * 8]     = v0;
        *(float4*)&vlds[px1 * 36 + g1 * 8 + 4] = v1;

        if (kk < 8) {                          // issue next kk's gathers now
            cur = mk(kk + 1, ndy, ndx);
            A0 = *(const float4*)(xg + cur.o00); A1 = *(const float4*)(xg + cur.o00 + 4);
            B0 = *(const float4*)(xg + cur.o01); B1 = *(const float4*)(xg + cur.o01 + 4);
            C0 = *(const float4*)(xg + cur.o10); C1 = *(const float4*)(xg + cur.o10 + 4);
            D0 = *(const float4*)(xg + cur.o11); D1 = *(const float4*)(xg + cur.o11 + 4);
            if (kk < 7) {
                ndy = ob[(2 * kk + 4) * HW_];
                ndx = ob[(2 * kk + 5) * HW_];
            }
        }
        __syncthreads();                       // v(kk) visible

        const float* wk = wt + (kk << 11) + (og << 4);   // wt[kk][.][16og]
        const float* vp = &vlds[px2 * 36];
#pragma unroll
        for (int j = 0; j < 8; ++j) {
            const float4 vv = *(const float4*)(vp + 4 * j);   // ds_read_b128
            const float vs[4] = {vv.x, vv.y, vv.z, vv.w};
#pragma unroll
            for (int e = 0; e < 4; ++e) {
                const float4* wr = (const float4*)(wk + ((j * 4 + e) << 6));
                const float4 w0 = wr[0], w1 = wr[1], w2 = wr[2], w3 = wr[3];
                const float vc = vs[e];
                acc[ 0] += vc * w0.x; acc[ 1] += vc * w0.y;
                acc[ 2] += vc * w0.z; acc[ 3] += vc * w0.w;
                acc[ 4] += vc * w1.x; acc[ 5] += vc * w1.y;
                acc[ 6] += vc * w1.z; acc[ 7] += vc * w1.w;
                acc[ 8] += vc * w2.x; acc[ 9] += vc * w2.y;
                acc[10] += vc * w2.z; acc[11] += vc * w2.w;
                acc[12] += vc * w3.x; acc[13] += vc * w3.y;
                acc[14] += vc * w3.z; acc[15] += vc * w3.w;
            }
        }
    }

    // bias + store (16 channels for this og, pixel rem2)
    const int rem2 = rb + px2;
    float* yp = y + ((size_t)b * COUT_ + og * 16) * HW_ + rem2;
#pragma unroll
    for (int q = 0; q < 16; ++q) {
        acc[q] += b_def[og * 16 + q];
        yp[q * HW_] = acc[q];
    }

    // fused BN stats: wave = (64 px, one og). Butterfly 16 channels.
    float ls = 0.f, lq = 0.f;
#pragma unroll
    for (int o = 0; o < 16; ++o) {
        float t = acc[o];
        float u = t * t;
#pragma unroll
        for (int s = 32; s; s >>= 1) {
            t += __shfl_xor(t, s, 64);
            u += __shfl_xor(u, s, 64);
        }
        if (lane == o) { ls = t; lq = u; }
    }
    if (lane < 16) {
        atomicAdd(&sum_bc[b * 64 + og * 16 + lane], ls);
        atomicAdd(&sumsq_bc[b * 64 + og * 16 + lane], lq);
    }
}

// ---------------------------------------------------------------------------
// Kernel 3: fused SE-MLP + affine(BN*SE) + ReLU + 2x2 maxpool.
// ---------------------------------------------------------------------------
__global__ __launch_bounds__(256) void k_finish(
    const float* __restrict__ y,
    const float* __restrict__ sum_bc, const float* __restrict__ sumsq_bc,
    const float* __restrict__ gamma, const float* __restrict__ beta,
    const float* __restrict__ fc1_w, const float* __restrict__ fc1_b,
    const float* __restrict__ fc2_w, const float* __restrict__ fc2_b,
    float* __restrict__ out)
{
    __shared__ float sal[256], sbb[256], sin_[256];
    const int tid = threadIdx.x;
    {
        const int b = tid >> 6, c = tid & 63;
        float ch_s = 0.f, ch_q = 0.f;
#pragma unroll
        for (int bb = 0; bb < 4; ++bb) {
            ch_s += sum_bc[bb * 64 + c];
            ch_q += sumsq_bc[bb * 64 + c];
        }
        const float invN = 1.f / (float)(B_ * HW_);
        const float mean = ch_s * invN;
        const float var  = ch_q * invN - mean * mean;
        const float a    = gamma[c] * rsqrtf(var + EPS_);
        const float bi   = beta[c] - mean * a;
        sin_[tid] = a * (sum_bc[tid] * (1.f / (float)HW_)) + bi;
        __syncthreads();
        float hv[4];
#pragma unroll
        for (int j = 0; j < 4; ++j) {
            float hs = fc1_b[j];
            for (int cc = 0; cc < 64; ++cc)
                hs += sin_[b * 64 + cc] * fc1_w[j * 64 + cc];
            hv[j] = fmaxf(hs, 0.f);
        }
        float o = fc2_b[c];
#pragma unroll
        for (int j = 0; j < 4; ++j) o += hv[j] * fc2_w[c * 4 + j];
        const float s = 1.f / (1.f + expf(-o));
        sal[tid] = a * s;
        sbb[tid] = bi * s;
    }
    __syncthreads();

    const int t    = blockIdx.x * 256 + tid;
    const int opix = t * 2;
    const int bc   = opix / (96 * 96);
    const int rem  = opix - bc * (96 * 96);
    const int oh   = rem / 96, ow = rem - oh * 96;   // ow even
    const float al = sal[bc], bb = sbb[bc];
    const float* yp = y + (size_t)bc * HW_ + (2 * oh) * W_ + 2 * ow;
    const float4 r0 = *(const float4*)yp;
    const float4 r1 = *(const float4*)(yp + W_);
    float2 st;
    st.x = fmaxf(fmaxf(fmaxf(fmaf(r0.x, al, bb), fmaf(r0.y, al, bb)),
                       fmaxf(fmaf(r1.x, al, bb), fmaf(r1.y, al, bb))), 0.f);
    st.y = fmaxf(fmaxf(fmaxf(fmaf(r0.z, al, bb), fmaf(r0.w, al, bb)),
                       fmaxf(fmaf(r1.z, al, bb), fmaf(r1.w, al, bb))), 0.f);
    *(float2*)(out + opix) = st;
}

// ---------------------------------------------------------------------------
extern "C" void kernel_launch(void* const* d_in, const int* in_sizes, int n_in,
                              void* d_out, int out_size, void* d_ws, size_t ws_size,
                              hipStream_t stream)
{
    const float* x     = (const float*)d_in[0];
    const float* w_off = (const float*)d_in[1];
    const float* b_off = (const float*)d_in[2];
    const float* w_def = (const float*)d_in[3];
    const float* b_def = (const float*)d_in[4];
    const float* gamma = (const float*)d_in[5];
    const float* beta  = (const float*)d_in[6];
    const float* fc1_w = (const float*)d_in[7];
    const float* fc1_b = (const float*)d_in[8];
    const float* fc2_w = (const float*)d_in[9];
    const float* fc2_b = (const float*)d_in[10];
    float* out = (float*)d_out;

    float* ws   = (float*)d_ws;
    float* offs   = ws;                          // 2,654,208 floats
    float* yb     = offs + 2654208;              // 9,437,184 floats
    float* xt     = yb + 9437184;                // 4,718,592 floats (NHWC x)
    float* wt_def = xt + 4718592;                // 18,432
    float* wt_off = wt_def + 18432;              // 5,760
    float* stats  = wt_off + 5760;               // 1,024
    float* sum_bc   = stats;
    float* sumsq_bc = stats + 256;

    k_pre     <<<dim3(NPIX_ / 256 + 97), dim3(256), 0, stream>>>(
                  x, w_def, w_off, xt, wt_def, wt_off, stats);
    k_conv_off<<<dim3(NPIX_ / 128), dim3(512), 0, stream>>>(xt, wt_off, b_off, offs);
    k_deform  <<<dim3(NPIX_ / 128), dim3(512), 0, stream>>>(xt, offs, wt_def, b_def,
                                                            yb, sum_bc, sumsq_bc);
    k_finish  <<<dim3(B_ * COUT_ * 96 * 96 / 512), dim3(256), 0, stream>>>(
                  yb, sum_bc, sumsq_bc, gamma, beta,
                  fc1_w, fc1_b, fc2_w, fc2_b, out);
}